// Round 3
// baseline (1879.694 us; speedup 1.0000x reference)
//
#include <hip/hip_runtime.h>

typedef _Float16 f16x8 __attribute__((ext_vector_type(8)));
typedef float f32x4 __attribute__((ext_vector_type(4)));

#define TT 512
#define BB 128
#define II 512
#define HH 512

__device__ __forceinline__ f16x8 cvt8(f32x4 a, f32x4 b) {
  f16x8 r;
  r[0] = (_Float16)a[0]; r[1] = (_Float16)a[1];
  r[2] = (_Float16)a[2]; r[3] = (_Float16)a[3];
  r[4] = (_Float16)b[0]; r[5] = (_Float16)b[1];
  r[6] = (_Float16)b[2]; r[7] = (_Float16)b[3];
  return r;
}

// ---------------- Phase 1: xw[t,b,:] = x[t,b,:] @ W_ih^T + b ----------------
__global__ __launch_bounds__(256) void xw_gemm(
    const float* __restrict__ X, const float* __restrict__ Wih,
    const float* __restrict__ bias, float* __restrict__ out) {
  __shared__ _Float16 As[128][40];
  __shared__ _Float16 Bs[128][40];
  const int tid = threadIdx.x;
  const int lane = tid & 63, wv = tid >> 6;
  const int l15 = lane & 15, lhi = lane >> 4;
  const int ntile = blockIdx.x & 3;
  const int mtile = blockIdx.x >> 2;
  const int M0 = mtile * 128, N0 = ntile * 128;
  const int wm = (wv & 1) * 64, wn = (wv >> 1) * 64;

  f32x4 acc[4][4];
#pragma unroll
  for (int ni = 0; ni < 4; ++ni) {
    const float bv = bias[N0 + wn + ni * 16 + l15];
#pragma unroll
    for (int mi = 0; mi < 4; ++mi) {
      acc[mi][ni][0] = bv; acc[mi][ni][1] = bv;
      acc[mi][ni][2] = bv; acc[mi][ni][3] = bv;
    }
  }
  const int srow = tid >> 1;
  const int shalf = (tid & 1) * 16;

  for (int k0 = 0; k0 < II; k0 += 32) {
    const float* ax = X + (size_t)(M0 + srow) * II + k0 + shalf;
    const float* bx = Wih + (size_t)(N0 + srow) * II + k0 + shalf;
    f32x4 a0 = *(const f32x4*)ax,       a1 = *(const f32x4*)(ax + 4);
    f32x4 a2 = *(const f32x4*)(ax + 8), a3 = *(const f32x4*)(ax + 12);
    f32x4 b0 = *(const f32x4*)bx,       b1 = *(const f32x4*)(bx + 4);
    f32x4 b2 = *(const f32x4*)(bx + 8), b3 = *(const f32x4*)(bx + 12);
    *(f16x8*)&As[srow][shalf]     = cvt8(a0, a1);
    *(f16x8*)&As[srow][shalf + 8] = cvt8(a2, a3);
    *(f16x8*)&Bs[srow][shalf]     = cvt8(b0, b1);
    *(f16x8*)&Bs[srow][shalf + 8] = cvt8(b2, b3);
    __syncthreads();
    f16x8 af[4], bf[4];
#pragma unroll
    for (int mi = 0; mi < 4; ++mi) af[mi] = *(const f16x8*)&As[wm + mi * 16 + l15][lhi * 8];
#pragma unroll
    for (int ni = 0; ni < 4; ++ni) bf[ni] = *(const f16x8*)&Bs[wn + ni * 16 + l15][lhi * 8];
#pragma unroll
    for (int mi = 0; mi < 4; ++mi)
#pragma unroll
      for (int ni = 0; ni < 4; ++ni)
        acc[mi][ni] = __builtin_amdgcn_mfma_f32_16x16x32_f16(af[mi], bf[ni], acc[mi][ni], 0, 0, 0);
    __syncthreads();
  }
#pragma unroll
  for (int mi = 0; mi < 4; ++mi)
#pragma unroll
    for (int ni = 0; ni < 4; ++ni) {
      const size_t rbase = (size_t)(M0 + wm + mi * 16 + lhi * 4) * HH + N0 + wn + ni * 16 + l15;
#pragma unroll
      for (int r = 0; r < 4; ++r) out[rbase + (size_t)r * HH] = acc[mi][ni][r];
    }
}

// ---------------- Phase 2: h_t = tanh(xw_t + h_{t-1} @ W_hh^T) ----------------
// 8 blocks x 16 batch rows, 512 threads = 8 waves (2/SIMD), wave owns 64 cols.
// W_hh fp16: k in [0,384) -> 48 B-frags/wave in regs (AGPR-able);
//            k in [384,512) -> 128 KB XOR-swizzled LDS.
// h DOUBLE-BUFFERED in LDS (2 x 16 KB swizzled fp16) -> ONE barrier per step:
// step t reads hb[t&1], writes hb[(t+1)&1]; a single RAW barrier also guards
// the WAR direction. tanh via Pade 7/6 poly (1 rcp, no exp). setprio around
// MFMA cluster. Global h stores sit after the LDS write; barrier drains lgkm
// only, so stores fly under the next step's MFMA phase.
__global__ __launch_bounds__(512, 2) void rnn_rec(
    const float* __restrict__ Whh,
    const float* __restrict__ xw,
    float* __restrict__ hout) {
  __shared__ char lds[163840];
  char* wbase = lds;             // [512 rows][256 B] swizzled fp16, k-local 0..127
  char* hb0 = lds + 131072;      // h buffer A: [16 rows][1024 B] swizzled fp16
  char* hb1 = lds + 147456;      // h buffer B
  const int tid = threadIdx.x;
  const int lane = tid & 63, wv = tid >> 6;   // wv 0..7
  const int l15 = lane & 15, lhi = lane >> 4;
  const int row0 = blockIdx.x * 16;
  const int col0 = wv * 64;

  // ---- stage W k-chunk [384,512) into swizzled LDS (fp32 -> fp16) ----
#pragma unroll
  for (int i = 0; i < 16; ++i) {
    const int u = i * 512 + tid;
    const int r = u >> 4;
    const int slot = u & 15;
    const float* src = Whh + (size_t)r * HH + 384 + slot * 8;
    f32x4 a = *(const f32x4*)src;
    f32x4 b = *(const f32x4*)(src + 4);
    *(f16x8*)(wbase + r * 256 + ((slot * 16) ^ ((r & 7) << 4))) = cvt8(a, b);
  }
  // ---- zero h buffer A (h_{-1} = 0; t=0 reads hb0) ----
  for (int i = tid; i < 4096; i += 512) ((unsigned int*)hb0)[i] = 0u;

  // ---- W register fragments, k in [0,384) ----
  f16x8 wreg[48];
#pragma unroll
  for (int ni = 0; ni < 4; ++ni) {
    const float* wr = Whh + (size_t)(col0 + ni * 16 + l15) * HH + lhi * 8;
#pragma unroll
    for (int kj = 0; kj < 12; ++kj) {
      const float* s = wr + kj * 32;
      wreg[ni * 12 + kj] = cvt8(*(const f32x4*)s, *(const f32x4*)(s + 4));
    }
  }

  // ---- first xw prefetch (t = 0) ----
  f32x4 pref[4];
  {
    const size_t base = (size_t)(row0 + lhi * 4) * HH + col0 + l15;
#pragma unroll
    for (int ni = 0; ni < 4; ++ni)
#pragma unroll
      for (int r = 0; r < 4; ++r)
        pref[ni][r] = xw[base + (size_t)r * HH + ni * 16];
  }
  __syncthreads();

  const int fa = ((l15 & 7) ^ ((l15 >> 3) << 1)) << 4;

  for (int t = 0; t < TT; ++t) {
    char* rb = (t & 1) ? hb1 : hb0;   // read h_{t-1}
    char* wb = (t & 1) ? hb0 : hb1;   // write h_t
    f32x4 acc[4];
#pragma unroll
    for (int ni = 0; ni < 4; ++ni) acc[ni] = pref[ni];
    // prefetch xw[t+1] under this step's MFMAs
    if (t + 1 < TT) {
      const size_t base = (size_t)(t + 1) * (BB * HH) + (size_t)(row0 + lhi * 4) * HH + col0 + l15;
#pragma unroll
      for (int ni = 0; ni < 4; ++ni)
#pragma unroll
        for (int r = 0; r < 4; ++r)
          pref[ni][r] = xw[base + (size_t)r * HH + ni * 16];
    }
    // ---- h @ W^T: 12 register k-frags + 4 LDS k-frags ----
    __builtin_amdgcn_s_setprio(1);
#pragma unroll
    for (int kj = 0; kj < 12; ++kj) {
      f16x8 af = *(const f16x8*)(rb + l15 * 1024 + ((kj * 64 + lhi * 16) ^ fa));
#pragma unroll
      for (int ni = 0; ni < 4; ++ni)
        acc[ni] = __builtin_amdgcn_mfma_f32_16x16x32_f16(af, wreg[ni * 12 + kj], acc[ni], 0, 0, 0);
    }
#pragma unroll
    for (int kj = 12; kj < 16; ++kj) {
      f16x8 af = *(const f16x8*)(rb + l15 * 1024 + ((kj * 64 + lhi * 16) ^ fa));
#pragma unroll
      for (int ni = 0; ni < 4; ++ni) {
        const int wrow = col0 + ni * 16 + l15;
        f16x8 bf = *(const f16x8*)(wbase + wrow * 256 +
                      ((((kj - 12) * 32 + lhi * 8) * 2) ^ ((wrow & 7) << 4)));
        acc[ni] = __builtin_amdgcn_mfma_f32_16x16x32_f16(af, bf, acc[ni], 0, 0, 0);
      }
    }
    __builtin_amdgcn_s_setprio(0);
    // ---- tanh (Pade 7/6, clamp +/-4.97) -> LDS h_t, then global stores ----
    const size_t obase = (size_t)t * (BB * HH) + (size_t)(row0 + lhi * 4) * HH + col0 + l15;
#pragma unroll
    for (int ni = 0; ni < 4; ++ni)
#pragma unroll
      for (int r = 0; r < 4; ++r) {
        const float v = acc[ni][r];
        const float xc = fminf(fmaxf(v, -4.97f), 4.97f);
        const float x2 = xc * xc;
        const float p = fmaf(x2, fmaf(x2, fmaf(x2, 1.0f, 378.0f), 17325.0f), 135135.0f) * xc;
        const float q = fmaf(x2, fmaf(x2, fmaf(x2, 28.0f, 3150.0f), 62370.0f), 135135.0f);
        const float th = p * __builtin_amdgcn_rcpf(q);
        acc[ni][r] = th;
        const int hrow = lhi * 4 + r;
        const int fw = ((hrow & 7) ^ ((hrow >> 3) << 1)) << 4;
        *(_Float16*)(wb + hrow * 1024 +
                     (((col0 + ni * 16 + l15) * 2) ^ fw)) = (_Float16)th;
      }
#pragma unroll
    for (int ni = 0; ni < 4; ++ni)
#pragma unroll
      for (int r = 0; r < 4; ++r) {
        const float th = acc[ni][r];
        hout[obase + (size_t)r * HH + ni * 16] = th;
        if (t == TT - 1)
          hout[(size_t)TT * BB * HH + (size_t)(row0 + lhi * 4 + r) * HH + col0 + ni * 16 + l15] = th;
      }
    // single barrier per step: h_t (LDS) written before anyone reads it;
    // lgkm-only drain keeps global stores + xw prefetch in flight.
    asm volatile("s_waitcnt lgkmcnt(0)" ::: "memory");
    __builtin_amdgcn_s_barrier();
    __builtin_amdgcn_sched_barrier(0);
  }
}

extern "C" void kernel_launch(void* const* d_in, const int* in_sizes, int n_in,
                              void* d_out, int out_size, void* d_ws, size_t ws_size,
                              hipStream_t stream) {
  (void)in_sizes; (void)n_in; (void)out_size; (void)d_ws; (void)ws_size;
  const float* x    = (const float*)d_in[0];
  const float* w_ih = (const float*)d_in[1];
  const float* w_hh = (const float*)d_in[2];
  const float* b    = (const float*)d_in[3];
  float* out = (float*)d_out;
  xw_gemm<<<dim3(2048), dim3(256), 0, stream>>>(x, w_ih, b, out);
  rnn_rec<<<dim3(8), dim3(512), 0, stream>>>(w_hh, out, out);
}